// Round 1
// baseline (108.764 us; speedup 1.0000x reference)
//
#include <hip/hip_runtime.h>

// WordSpanLoss: B=16, F=512, T=8192, W=4096, SPACE_TOKEN=63, STRIDE=2
// inputs: d_in[0] word_preds f32 (B,F,W); d_in[1] char_features f32 (B,F,T);
//         d_in[2] target_chars i32 (B,T). out: 1 float.

constexpr int SPACE_TOKEN = 63;
constexpr int B = 16;
constexpr int FDIM = 512;
constexpr int T = 8192;
constexpr int W = 4096;

// ---------------- kernel 1: find space positions per batch ----------------
__global__ __launch_bounds__(256) void k_find_spaces(
    const int* __restrict__ chars, int* __restrict__ spacePos,
    int* __restrict__ nspaces, int* __restrict__ validCount) {
  const int b = blockIdx.x;
  const int* c = chars + (size_t)b * T;
  int* pos = spacePos + (size_t)b * T;
  __shared__ int s_wave[4];
  __shared__ int s_run;
  __shared__ int s_red[4];
  const int tid = threadIdx.x;
  const int lane = tid & 63;
  const int wid = tid >> 6;
  if (tid == 0) s_run = 0;
  __syncthreads();
  for (int base = 0; base < T; base += 256) {
    const int t = base + tid;
    const bool isSp = (c[t] == SPACE_TOKEN);
    unsigned long long m = __ballot(isSp ? 1 : 0);
    const int rank = __popcll(m & ((1ULL << lane) - 1ULL));
    if (lane == 0) s_wave[wid] = __popcll(m);
    __syncthreads();
    int prefix = s_run;
    for (int w = 0; w < wid; ++w) prefix += s_wave[w];
    if (isSp) pos[prefix + rank] = t;
    __syncthreads();
    if (tid == 0) s_run += s_wave[0] + s_wave[1] + s_wave[2] + s_wave[3];
    __syncthreads();
  }
  const int S = s_run;
  if (tid == 0) nspaces[b] = S;
  // count valid spans: k in [0, S-1), non-empty (strictly-between chars exist)
  int vc = 0;
  for (int k = tid; k < S - 1; k += 256) {
    if (pos[k + 1] - pos[k] > 1) vc++;
  }
  for (int o = 32; o > 0; o >>= 1) vc += __shfl_down(vc, o);
  if (lane == 0) s_red[wid] = vc;
  __syncthreads();
  if (tid == 0) validCount[b] = s_red[0] + s_red[1] + s_red[2] + s_red[3];
}

// ------------- kernel 2: per-(b,f) partial sum of squared error -----------
__global__ __launch_bounds__(256) void k_span_loss(
    const float* __restrict__ wp, const float* __restrict__ cf,
    const int* __restrict__ spacePos, const int* __restrict__ nspaces,
    float* __restrict__ partials) {
  const int idx = blockIdx.x;          // b*FDIM + f
  const int b = idx >> 9;              // FDIM = 512
  extern __shared__ float row[];       // T floats = 32 KB
  __shared__ float s_red[4];
  const float* src = cf + (size_t)idx * T;
  const float4* s4 = (const float4*)src;
  float4* r4 = (float4*)row;
  const int tid = threadIdx.x;
  #pragma unroll
  for (int i = 0; i < T / 4 / 256; ++i) r4[tid + i * 256] = s4[tid + i * 256];
  __syncthreads();
  const int S = nspaces[b];
  const int* pos = spacePos + (size_t)b * T;
  const float* wrow = wp + (size_t)idx * W;
  float acc = 0.f;
  for (int k = tid; k < S - 1; k += 256) {
    const int p0 = pos[k];
    const int p1 = pos[k + 1];
    const int cnt = p1 - p0 - 1;
    if (cnt > 0) {
      float s = 0.f;
      for (int t = p0 + 1; t < p1; ++t) s += row[t];
      const float mean = s / (float)cnt;
      const float d = wrow[p0 >> 1] - mean;   // word_pos = p0 / STRIDE
      acc += d * d;
    }
  }
  const int lane = tid & 63;
  const int wid = tid >> 6;
  for (int o = 32; o > 0; o >>= 1) acc += __shfl_down(acc, o);
  if (lane == 0) s_red[wid] = acc;
  __syncthreads();
  if (tid == 0) partials[idx] = s_red[0] + s_red[1] + s_red[2] + s_red[3];
}

// ---------------- kernel 3: deterministic final reduction ----------------
__global__ __launch_bounds__(256) void k_finalize(
    const float* __restrict__ partials, const int* __restrict__ validCount,
    float* __restrict__ out) {
  __shared__ float s_red[4];
  __shared__ int s_cnt[4];
  const int tid = threadIdx.x;
  const int lane = tid & 63;
  const int wid = tid >> 6;
  float s = 0.f;
  for (int i = tid; i < B * FDIM; i += 256) s += partials[i];
  int cnt = 0;
  for (int i = tid; i < B; i += 256) cnt += validCount[i];
  for (int o = 32; o > 0; o >>= 1) {
    s += __shfl_down(s, o);
    cnt += __shfl_down(cnt, o);
  }
  if (lane == 0) { s_red[wid] = s; s_cnt[wid] = cnt; }
  __syncthreads();
  if (tid == 0) {
    const float total = s_red[0] + s_red[1] + s_red[2] + s_red[3];
    const int c = s_cnt[0] + s_cnt[1] + s_cnt[2] + s_cnt[3];
    out[0] = (c > 0) ? total / ((float)FDIM * (float)c) : 0.f;
  }
}

extern "C" void kernel_launch(void* const* d_in, const int* in_sizes, int n_in,
                              void* d_out, int out_size, void* d_ws, size_t ws_size,
                              hipStream_t stream) {
  const float* wp = (const float*)d_in[0];
  const float* cf = (const float*)d_in[1];
  const int* chars = (const int*)d_in[2];
  float* out = (float*)d_out;

  // workspace layout
  char* ws = (char*)d_ws;
  int* spacePos = (int*)ws;                            // B*T ints = 512 KB
  int* nspaces = (int*)(ws + (size_t)B * T * 4);       // B ints
  int* validCount = nspaces + B;                       // B ints
  float* partials = (float*)(validCount + B);          // B*FDIM floats

  k_find_spaces<<<B, 256, 0, stream>>>(chars, spacePos, nspaces, validCount);
  k_span_loss<<<B * FDIM, 256, T * sizeof(float), stream>>>(wp, cf, spacePos,
                                                            nspaces, partials);
  k_finalize<<<1, 256, 0, stream>>>(partials, validCount, out);
}

// Round 3
// 93.844 us; speedup vs baseline: 1.1590x; 1.1590x over previous
//
#include <hip/hip_runtime.h>

// WordSpanLoss: B=16, F=512, T=8192, W=4096, SPACE_TOKEN=63, STRIDE=2
// inputs: d_in[0] word_preds f32 (B,F,W); d_in[1] char_features f32 (B,F,T);
//         d_in[2] target_chars i32 (B,T). out: 1 float.

constexpr int SPACE_TOKEN = 63;
constexpr int B = 16;
constexpr int FDIM = 512;
constexpr int T = 8192;
constexpr int W = 4096;

// ---------------- kernel 1: find space positions per batch ----------------
__global__ __launch_bounds__(256) void k_find_spaces(
    const int* __restrict__ chars, int* __restrict__ spacePos,
    int* __restrict__ nspaces, int* __restrict__ validCount) {
  const int b = blockIdx.x;
  const int* c = chars + (size_t)b * T;
  int* pos = spacePos + (size_t)b * T;
  __shared__ int s_wave[4];
  __shared__ int s_run;
  __shared__ int s_red[4];
  const int tid = threadIdx.x;
  const int lane = tid & 63;
  const int wid = tid >> 6;
  if (tid == 0) s_run = 0;
  __syncthreads();
  for (int base = 0; base < T; base += 256) {
    const int t = base + tid;
    const bool isSp = (c[t] == SPACE_TOKEN);
    unsigned long long m = __ballot(isSp ? 1 : 0);
    const int rank = __popcll(m & ((1ULL << lane) - 1ULL));
    if (lane == 0) s_wave[wid] = __popcll(m);
    __syncthreads();
    int prefix = s_run;
    for (int w = 0; w < wid; ++w) prefix += s_wave[w];
    if (isSp) pos[prefix + rank] = t;
    __syncthreads();
    if (tid == 0) s_run += s_wave[0] + s_wave[1] + s_wave[2] + s_wave[3];
    __syncthreads();
  }
  const int S = s_run;
  if (tid == 0) nspaces[b] = S;
  int vc = 0;
  for (int k = tid; k < S - 1; k += 256) {
    if (pos[k + 1] - pos[k] > 1) vc++;
  }
  for (int o = 32; o > 0; o >>= 1) vc += __shfl_down(vc, o);
  if (lane == 0) s_red[wid] = vc;
  __syncthreads();
  if (tid == 0) validCount[b] = s_red[0] + s_red[1] + s_red[2] + s_red[3];
}

// ------------- kernel 2: per-(b,f) partial sum of squared error -----------
// Strategy: block-wide hierarchical prefix sum of the 8192-float row, then
// each span sum = P(p1-1) - P(p0) (2 LDS reads instead of ~63 serial ones).
// LDS float4 slots are XOR-swizzled (slot ^ ((slot>>3)&7)) so BOTH the
// coalesced interleaved write phase and the per-thread chunked read phase
// spread evenly over all 8 bank groups.
__device__ __forceinline__ int swz(int u) { return u ^ ((u >> 3) & 7); }

__global__ __launch_bounds__(256) void k_span_loss(
    const float* __restrict__ wp, const float* __restrict__ cf,
    const int* __restrict__ spacePos, const int* __restrict__ nspaces,
    float* __restrict__ partials) {
  const int idx = blockIdx.x;          // b*FDIM + f
  const int b = idx >> 9;              // FDIM = 512
  __shared__ float rowf[T];            // 32 KB, swizzled float4 layout
  __shared__ float csum[256];          // per-chunk totals
  __shared__ float cexc[256];          // exclusive chunk prefix
  __shared__ float s_red[4];
  const int tid = threadIdx.x;
  const float4* s4 = (const float4*)(cf + (size_t)idx * T);
  float4* r4 = (float4*)rowf;

  // phase a: coalesced global -> swizzled LDS (1 KB per instr per wave)
  #pragma unroll
  for (int i = 0; i < 8; ++i) {
    const int u = tid + i * 256;
    r4[swz(u)] = s4[u];
  }
  __syncthreads();

  // phase b: per-thread chunk of 32 floats -> in-register inclusive prefix
  float4 v[8];
  #pragma unroll
  for (int i = 0; i < 8; ++i) v[i] = r4[swz(tid * 8 + i)];
  float run = 0.f;
  #pragma unroll
  for (int i = 0; i < 8; ++i) {
    v[i].x = (run += v[i].x);
    v[i].y = (run += v[i].y);
    v[i].z = (run += v[i].z);
    v[i].w = (run += v[i].w);
  }
  #pragma unroll
  for (int i = 0; i < 8; ++i) r4[swz(tid * 8 + i)] = v[i];
  csum[tid] = run;
  __syncthreads();

  // phase c: wave 0 scans the 256 chunk totals -> exclusive offsets
  if (tid < 64) {
    const float4 sv = ((const float4*)csum)[tid];   // coalesced b128
    const float l1 = sv.x + sv.y;
    const float l2 = l1 + sv.z;
    const float tot = l2 + sv.w;
    float inc = tot;
    #pragma unroll
    for (int o = 1; o < 64; o <<= 1) {
      const float n = __shfl_up(inc, o);
      if (tid >= o) inc += n;
    }
    const float exc = inc - tot;
    cexc[tid * 4 + 0] = exc;
    cexc[tid * 4 + 1] = exc + sv.x;
    cexc[tid * 4 + 2] = exc + l1;
    cexc[tid * 4 + 3] = exc + l2;
  }
  __syncthreads();

  // phase d: spans. P(t) = rowf[phys(t)] + cexc[t>>5]  (inclusive prefix)
  const int S = nspaces[b];
  const int* pos = spacePos + (size_t)b * T;
  const float* wrow = wp + (size_t)idx * W;
  float acc = 0.f;
  for (int k = tid; k < S - 1; k += 256) {
    const int p0 = pos[k];
    const int p1 = pos[k + 1];
    const int cnt = p1 - p0 - 1;
    if (cnt > 0) {
      const int ta = p1 - 1;
      const float Pa = rowf[(swz(ta >> 2) << 2) | (ta & 3)] + cexc[ta >> 5];
      const float Pb = rowf[(swz(p0 >> 2) << 2) | (p0 & 3)] + cexc[p0 >> 5];
      const float mean = (Pa - Pb) / (float)cnt;
      const float d = wrow[p0 >> 1] - mean;   // word_pos = p0 / STRIDE
      acc += d * d;
    }
  }
  const int lane = tid & 63;
  const int wid = tid >> 6;
  for (int o = 32; o > 0; o >>= 1) acc += __shfl_down(acc, o);
  if (lane == 0) s_red[wid] = acc;
  __syncthreads();
  if (tid == 0) partials[idx] = s_red[0] + s_red[1] + s_red[2] + s_red[3];
}

// ---------------- kernel 3: deterministic final reduction ----------------
__global__ __launch_bounds__(256) void k_finalize(
    const float* __restrict__ partials, const int* __restrict__ validCount,
    float* __restrict__ out) {
  __shared__ float s_red[4];
  __shared__ int s_cnt[4];
  const int tid = threadIdx.x;
  const int lane = tid & 63;
  const int wid = tid >> 6;
  float s = 0.f;
  for (int i = tid; i < B * FDIM; i += 256) s += partials[i];
  int cnt = 0;
  for (int i = tid; i < B; i += 256) cnt += validCount[i];
  for (int o = 32; o > 0; o >>= 1) {
    s += __shfl_down(s, o);
    cnt += __shfl_down(cnt, o);
  }
  if (lane == 0) { s_red[wid] = s; s_cnt[wid] = cnt; }
  __syncthreads();
  if (tid == 0) {
    const float total = s_red[0] + s_red[1] + s_red[2] + s_red[3];
    const int c = s_cnt[0] + s_cnt[1] + s_cnt[2] + s_cnt[3];
    out[0] = (c > 0) ? total / ((float)FDIM * (float)c) : 0.f;
  }
}

extern "C" void kernel_launch(void* const* d_in, const int* in_sizes, int n_in,
                              void* d_out, int out_size, void* d_ws, size_t ws_size,
                              hipStream_t stream) {
  const float* wp = (const float*)d_in[0];
  const float* cf = (const float*)d_in[1];
  const int* chars = (const int*)d_in[2];
  float* out = (float*)d_out;

  char* ws = (char*)d_ws;
  int* spacePos = (int*)ws;                            // B*T ints = 512 KB
  int* nspaces = (int*)(ws + (size_t)B * T * 4);       // B ints
  int* validCount = nspaces + B;                       // B ints
  float* partials = (float*)(validCount + B);          // B*FDIM floats

  k_find_spaces<<<B, 256, 0, stream>>>(chars, spacePos, nspaces, validCount);
  k_span_loss<<<B * FDIM, 256, 0, stream>>>(wp, cf, spacePos, nspaces, partials);
  k_finalize<<<1, 256, 0, stream>>>(partials, validCount, out);
}

// Round 4
// 74.568 us; speedup vs baseline: 1.4586x; 1.2585x over previous
//
#include <hip/hip_runtime.h>

// WordSpanLoss: B=16, F=512, T=8192, W=4096, SPACE_TOKEN=63, STRIDE=2
// inputs: d_in[0] word_preds f32 (B,F,W); d_in[1] char_features f32 (B,F,T);
//         d_in[2] target_chars i32 (B,T). out: 1 float.

constexpr int SPACE_TOKEN = 63;
constexpr int B = 16;
constexpr int FDIM = 512;
constexpr int T = 8192;
constexpr int W = 4096;

// ------------- kernel 1: single-pass space finder (1024 thr/batch) --------
// Each thread owns 8 consecutive chars in registers. Block-wide scan of
// per-thread space counts -> scatter positions. validCount computed WITHOUT
// re-reading pos: invalid spans (k < S-1) are exactly adjacent space pairs,
// so validCount = max(S-1,0) - #{t : c[t]==63 && c[t+1]==63}.
__global__ __launch_bounds__(1024) void k_find_spaces(
    const int* __restrict__ chars, int* __restrict__ spacePos,
    int* __restrict__ nspaces, int* __restrict__ validCount) {
  const int b = blockIdx.x;
  const int* c = chars + (size_t)b * T;
  int* pos = spacePos + (size_t)b * T;
  __shared__ int s_wtot[16];
  __shared__ int s_wpair[16];
  const int tid = threadIdx.x;
  const int lane = tid & 63;
  const int wid = tid >> 6;

  const int4* c4 = (const int4*)c;
  const int4 a0 = c4[tid * 2];
  const int4 a1 = c4[tid * 2 + 1];
  int v[8] = {a0.x, a0.y, a0.z, a0.w, a1.x, a1.y, a1.z, a1.w};
  // boundary char for pair detection (next thread's first char)
  int nxt = SPACE_TOKEN + 1;
  if (tid < 1023) nxt = c[tid * 8 + 8];

  int cnt = 0;
  int pairs = 0;
  #pragma unroll
  for (int i = 0; i < 8; ++i) cnt += (v[i] == SPACE_TOKEN);
  #pragma unroll
  for (int i = 0; i < 7; ++i)
    pairs += (v[i] == SPACE_TOKEN) && (v[i + 1] == SPACE_TOKEN);
  pairs += (v[7] == SPACE_TOKEN) && (nxt == SPACE_TOKEN);

  // wave inclusive scan of cnt; wave reduce of pairs
  int inc = cnt;
  int pr = pairs;
  #pragma unroll
  for (int o = 1; o < 64; o <<= 1) {
    const int n = __shfl_up(inc, o);
    if (lane >= o) inc += n;
  }
  #pragma unroll
  for (int o = 32; o > 0; o >>= 1) pr += __shfl_down(pr, o);
  if (lane == 63) s_wtot[wid] = inc;
  if (lane == 0) s_wpair[wid] = pr;
  __syncthreads();
  int wexc = 0;
  for (int w = 0; w < wid; ++w) wexc += s_wtot[w];
  int base = wexc + inc - cnt;  // exclusive prefix for this thread
  #pragma unroll
  for (int i = 0; i < 8; ++i)
    if (v[i] == SPACE_TOKEN) pos[base++] = tid * 8 + i;
  if (tid == 0) {
    int S = 0, P = 0;
    for (int w = 0; w < 16; ++w) { S += s_wtot[w]; P += s_wpair[w]; }
    nspaces[b] = S;
    validCount[b] = (S > 1 ? S - 1 : 0) - P;
  }
}

// ------------- kernel 2: per-(b,f) partial sum of squared error -----------
// Hierarchical prefix sum of the row; span sum = P(p1-1) - P(p0).
// Staging via global_load_lds with PRE-SWIZZLED SOURCE (swz is an involution,
// so LDS slot swz(u) holds src[u] — identical physical layout to the proven
// explicit-load version). Span data (pos, wrow) prefetched into registers at
// kernel entry so the scattered wrow HBM latency hides under staging+prefix.
__device__ __forceinline__ int swz(int u) { return u ^ ((u >> 3) & 7); }

__global__ __launch_bounds__(256) void k_span_loss(
    const float* __restrict__ wp, const float* __restrict__ cf,
    const int* __restrict__ spacePos, const int* __restrict__ nspaces,
    float* __restrict__ partials) {
  const int idx = blockIdx.x;          // b*FDIM + f
  const int b = idx >> 9;              // FDIM = 512
  __shared__ float rowf[T];            // 32 KB, swizzled float4 layout
  __shared__ float csum[256];
  __shared__ float cexc[256];
  __shared__ float s_red[4];
  const int tid = threadIdx.x;
  const int lane = tid & 63;
  const int wid = tid >> 6;
  const float4* s4 = (const float4*)(cf + (size_t)idx * T);
  float4* r4 = (float4*)rowf;

  // phase a: DMA global -> LDS, source pre-swizzled, LDS linear per-wave
  #pragma unroll
  for (int i = 0; i < 8; ++i) {
    const int u = i * 256 + tid;                    // linear LDS slot
    const float4* gsrc = s4 + swz(u);               // per-lane global addr
    float4* ldst = r4 + (i * 256 + wid * 64);       // wave-uniform base
    __builtin_amdgcn_global_load_lds(
        (const __attribute__((address_space(1))) void*)(const void*)gsrc,
        (__attribute__((address_space(3))) void*)(void*)ldst, 16, 0, 0);
  }

  // prefetch span data (overlaps with the DMA above)
  const int* pos = spacePos + (size_t)b * T;
  const float* wrow = wp + (size_t)idx * W;
  const int S = nspaces[b];
  const int p0r = pos[tid];            // unconditional: buffer always T ints
  const int p1r = pos[tid + 1];
  const float wv = wrow[(p0r >> 1) & (W - 1)];   // clamped; discarded if k>=S-1

  __syncthreads();   // drains DMA (vmcnt) + barrier

  // phase b: per-thread chunk of 32 floats -> in-register inclusive prefix
  float4 v[8];
  #pragma unroll
  for (int i = 0; i < 8; ++i) v[i] = r4[swz(tid * 8 + i)];
  float run = 0.f;
  #pragma unroll
  for (int i = 0; i < 8; ++i) {
    v[i].x = (run += v[i].x);
    v[i].y = (run += v[i].y);
    v[i].z = (run += v[i].z);
    v[i].w = (run += v[i].w);
  }
  #pragma unroll
  for (int i = 0; i < 8; ++i) r4[swz(tid * 8 + i)] = v[i];
  csum[tid] = run;
  __syncthreads();

  // phase c: wave 0 scans the 256 chunk totals -> exclusive offsets
  if (tid < 64) {
    const float4 sv = ((const float4*)csum)[tid];
    const float l1 = sv.x + sv.y;
    const float l2 = l1 + sv.z;
    const float tot = l2 + sv.w;
    float inc = tot;
    #pragma unroll
    for (int o = 1; o < 64; o <<= 1) {
      const float n = __shfl_up(inc, o);
      if (tid >= o) inc += n;
    }
    const float exc = inc - tot;
    ((float4*)cexc)[tid] = make_float4(exc, exc + sv.x, exc + l1, exc + l2);
  }
  __syncthreads();

  // phase d: spans, all from registers + LDS
  float acc = 0.f;
  if (tid < S - 1) {
    const int cnt = p1r - p0r - 1;
    if (cnt > 0) {
      const int ta = p1r - 1;
      const float Pa = rowf[(swz(ta >> 2) << 2) | (ta & 3)] + cexc[ta >> 5];
      const float Pb = rowf[(swz(p0r >> 2) << 2) | (p0r & 3)] + cexc[p0r >> 5];
      const float mean = (Pa - Pb) / (float)cnt;
      const float d = wv - mean;
      acc += d * d;
    }
  }
  // rare tail (S-1 > 256): direct loads, correctness path
  for (int k = tid + 256; k < S - 1; k += 256) {
    const int p0 = pos[k];
    const int p1 = pos[k + 1];
    const int cnt = p1 - p0 - 1;
    if (cnt > 0) {
      const int ta = p1 - 1;
      const float Pa = rowf[(swz(ta >> 2) << 2) | (ta & 3)] + cexc[ta >> 5];
      const float Pb = rowf[(swz(p0 >> 2) << 2) | (p0 & 3)] + cexc[p0 >> 5];
      const float mean = (Pa - Pb) / (float)cnt;
      const float d = wrow[p0 >> 1] - mean;
      acc += d * d;
    }
  }
  #pragma unroll
  for (int o = 32; o > 0; o >>= 1) acc += __shfl_down(acc, o);
  if (lane == 0) s_red[wid] = acc;
  __syncthreads();
  if (tid == 0) partials[idx] = s_red[0] + s_red[1] + s_red[2] + s_red[3];
}

// ---------------- kernel 3: deterministic final reduction ----------------
__global__ __launch_bounds__(256) void k_finalize(
    const float* __restrict__ partials, const int* __restrict__ validCount,
    float* __restrict__ out) {
  __shared__ float s_red[4];
  __shared__ int s_cnt[4];
  const int tid = threadIdx.x;
  const int lane = tid & 63;
  const int wid = tid >> 6;
  float s = 0.f;
  for (int i = tid; i < B * FDIM; i += 256) s += partials[i];
  int cnt = 0;
  for (int i = tid; i < B; i += 256) cnt += validCount[i];
  for (int o = 32; o > 0; o >>= 1) {
    s += __shfl_down(s, o);
    cnt += __shfl_down(cnt, o);
  }
  if (lane == 0) { s_red[wid] = s; s_cnt[wid] = cnt; }
  __syncthreads();
  if (tid == 0) {
    const float total = s_red[0] + s_red[1] + s_red[2] + s_red[3];
    const int c = s_cnt[0] + s_cnt[1] + s_cnt[2] + s_cnt[3];
    out[0] = (c > 0) ? total / ((float)FDIM * (float)c) : 0.f;
  }
}

extern "C" void kernel_launch(void* const* d_in, const int* in_sizes, int n_in,
                              void* d_out, int out_size, void* d_ws, size_t ws_size,
                              hipStream_t stream) {
  const float* wp = (const float*)d_in[0];
  const float* cf = (const float*)d_in[1];
  const int* chars = (const int*)d_in[2];
  float* out = (float*)d_out;

  char* ws = (char*)d_ws;
  int* spacePos = (int*)ws;                            // B*T ints = 512 KB
  int* nspaces = (int*)(ws + (size_t)B * T * 4);       // B ints
  int* validCount = nspaces + B;                       // B ints
  float* partials = (float*)(validCount + B);          // B*FDIM floats

  k_find_spaces<<<B, 1024, 0, stream>>>(chars, spacePos, nspaces, validCount);
  k_span_loss<<<B * FDIM, 256, 0, stream>>>(wp, cf, spacePos, nspaces, partials);
  k_finalize<<<1, 256, 0, stream>>>(partials, validCount, out);
}

// Round 6
// 74.371 us; speedup vs baseline: 1.4625x; 1.0027x over previous
//
#include <hip/hip_runtime.h>

// WordSpanLoss: B=16, F=512, T=8192, W=4096, SPACE_TOKEN=63, STRIDE=2
// inputs: d_in[0] word_preds f32 (B,F,W); d_in[1] char_features f32 (B,F,T);
//         d_in[2] target_chars i32 (B,T). out: 1 float.

constexpr int SPACE_TOKEN = 63;
constexpr int B = 16;
constexpr int FDIM = 512;
constexpr int T = 8192;
constexpr int W = 4096;
constexpr int ROWS = 8;                   // f-rows per span_loss block
constexpr int NPART = B * FDIM / ROWS;    // 1024 partials

// ------------- kernel 1: single-pass space finder (1024 thr/batch) --------
__global__ __launch_bounds__(1024) void k_find_spaces(
    const int* __restrict__ chars, int* __restrict__ spacePos,
    int* __restrict__ nspaces, int* __restrict__ validCount) {
  const int b = blockIdx.x;
  const int* c = chars + (size_t)b * T;
  int* pos = spacePos + (size_t)b * T;
  __shared__ int s_wtot[16];
  __shared__ int s_wpair[16];
  const int tid = threadIdx.x;
  const int lane = tid & 63;
  const int wid = tid >> 6;

  const int4* c4 = (const int4*)c;
  const int4 a0 = c4[tid * 2];
  const int4 a1 = c4[tid * 2 + 1];
  int v[8] = {a0.x, a0.y, a0.z, a0.w, a1.x, a1.y, a1.z, a1.w};
  int nxt = SPACE_TOKEN + 1;
  if (tid < 1023) nxt = c[tid * 8 + 8];

  int cnt = 0, pairs = 0;
  #pragma unroll
  for (int i = 0; i < 8; ++i) cnt += (v[i] == SPACE_TOKEN);
  #pragma unroll
  for (int i = 0; i < 7; ++i)
    pairs += (v[i] == SPACE_TOKEN) && (v[i + 1] == SPACE_TOKEN);
  pairs += (v[7] == SPACE_TOKEN) && (nxt == SPACE_TOKEN);

  int inc = cnt, pr = pairs;
  #pragma unroll
  for (int o = 1; o < 64; o <<= 1) {
    const int n = __shfl_up(inc, o);
    if (lane >= o) inc += n;
  }
  #pragma unroll
  for (int o = 32; o > 0; o >>= 1) pr += __shfl_down(pr, o);
  if (lane == 63) s_wtot[wid] = inc;
  if (lane == 0) s_wpair[wid] = pr;
  __syncthreads();
  int wexc = 0;
  for (int w = 0; w < wid; ++w) wexc += s_wtot[w];
  int base = wexc + inc - cnt;
  #pragma unroll
  for (int i = 0; i < 8; ++i)
    if (v[i] == SPACE_TOKEN) pos[base++] = tid * 8 + i;
  if (tid == 0) {
    int S = 0, P = 0;
    for (int w = 0; w < 16; ++w) { S += s_wtot[w]; P += s_wpair[w]; }
    nspaces[b] = S;
    validCount[b] = (S > 1 ? S - 1 : 0) - P;
  }
}

// ------------- kernel 2: multi-row pipelined span loss --------------------
// 8 f-rows (same batch) per block; 2x32KB LDS double-buffer; counted
// vmcnt(8) keeps next row's global_load_lds in flight across barriers
// (T3+T4). Physical per-row layout identical to the proven R4 kernel
// (pre-swizzled source, linear LDS dest; swz is an involution).
__device__ __forceinline__ int swz(int u) { return u ^ ((u >> 3) & 7); }

// barrier helpers with explicit waitcnt + compiler memory fences (rule #18)
#define BAR_VM8() do { asm volatile("s_waitcnt vmcnt(8)" ::: "memory"); \
  __builtin_amdgcn_s_barrier(); asm volatile("" ::: "memory"); } while (0)
#define BAR_VM0() do { asm volatile("s_waitcnt vmcnt(0)" ::: "memory"); \
  __builtin_amdgcn_s_barrier(); asm volatile("" ::: "memory"); } while (0)
#define BAR_LGKM() do { asm volatile("s_waitcnt lgkmcnt(0)" ::: "memory"); \
  __builtin_amdgcn_s_barrier(); asm volatile("" ::: "memory"); } while (0)

__device__ __forceinline__ void stage_row(const float4* __restrict__ src,
                                          float* dst, int tid, int wid) {
  float4* d4 = (float4*)dst;
  #pragma unroll
  for (int i = 0; i < 8; ++i) {
    const int u = i * 256 + tid;                 // linear LDS slot
    const float4* gsrc = src + swz(u);           // per-lane swizzled source
    float4* ldst = d4 + (i * 256 + wid * 64);    // wave-uniform base
    __builtin_amdgcn_global_load_lds(
        (const __attribute__((address_space(1))) void*)(const void*)gsrc,
        (__attribute__((address_space(3))) void*)(void*)ldst, 16, 0, 0);
  }
}

__global__ __launch_bounds__(256) void k_span_loss(
    const float* __restrict__ wp, const float* __restrict__ cf,
    const int* __restrict__ spacePos, const int* __restrict__ nspaces,
    float* __restrict__ partials) {
  const int blk = blockIdx.x;          // 0..NPART-1
  const int row0 = blk * ROWS;         // first (b,f) row; ROWS | FDIM
  const int b = row0 >> 9;
  __shared__ alignas(16) float buf[2][T];       // 64 KB
  __shared__ alignas(16) float csum[256];
  __shared__ alignas(16) float cexc[256];
  __shared__ float s_red[4];
  const int tid = threadIdx.x;
  const int lane = tid & 63;
  const int wid = tid >> 6;

  // prologue: DMA row 0 first (oldest in vmcnt), then register prefetches
  stage_row((const float4*)(cf + (size_t)row0 * T), buf[0], tid, wid);

  const int* pos = spacePos + (size_t)b * T;
  const int S = nspaces[b];
  const int p0r = pos[tid];
  const int p1r = pos[tid + 1];
  const int gidx = (p0r >> 1) & (W - 1);        // clamped; junk if tid>=S-1
  float wv[ROWS];
  #pragma unroll
  for (int r = 0; r < ROWS; ++r)
    wv[r] = wp[(size_t)(row0 + r) * W + gidx];

  float acc = 0.f;
  #pragma unroll 1
  for (int r = 0; r < ROWS; ++r) {
    // issue next row's DMA (stays in flight across the barriers below)
    if (r + 1 < ROWS)
      stage_row((const float4*)(cf + (size_t)(row0 + r + 1) * T),
                buf[(r + 1) & 1], tid, wid);
    // wait: everything older than the 8 newest (= next row's DMA) retired
    if (r + 1 < ROWS) { BAR_VM8(); } else { BAR_VM0(); }

    float* rowf = buf[r & 1];
    float4* r4 = (float4*)rowf;

    // phase b: per-thread 32-float in-register inclusive prefix
    float4 v[8];
    #pragma unroll
    for (int i = 0; i < 8; ++i) v[i] = r4[swz(tid * 8 + i)];
    float run = 0.f;
    #pragma unroll
    for (int i = 0; i < 8; ++i) {
      v[i].x = (run += v[i].x);
      v[i].y = (run += v[i].y);
      v[i].z = (run += v[i].z);
      v[i].w = (run += v[i].w);
    }
    #pragma unroll
    for (int i = 0; i < 8; ++i) r4[swz(tid * 8 + i)] = v[i];
    csum[tid] = run;
    BAR_LGKM();

    // phase c: wave 0 scans 256 chunk totals -> exclusive offsets
    if (tid < 64) {
      const float4 sv = ((const float4*)csum)[tid];
      const float l1 = sv.x + sv.y;
      const float l2 = l1 + sv.z;
      const float tot = l2 + sv.w;
      float inc = tot;
      #pragma unroll
      for (int o = 1; o < 64; o <<= 1) {
        const float n = __shfl_up(inc, o);
        if (tid >= o) inc += n;
      }
      const float exc = inc - tot;
      ((float4*)cexc)[tid] = make_float4(exc, exc + sv.x, exc + l1, exc + l2);
    }
    BAR_LGKM();

    // phase d: span evaluation from registers + LDS
    if (tid < S - 1) {
      const int cnt = p1r - p0r - 1;
      if (cnt > 0) {
        const int ta = p1r - 1;
        const float Pa = rowf[(swz(ta >> 2) << 2) | (ta & 3)] + cexc[ta >> 5];
        const float Pb = rowf[(swz(p0r >> 2) << 2) | (p0r & 3)] + cexc[p0r >> 5];
        const float mean = (Pa - Pb) / (float)cnt;
        const float d = wv[r] - mean;
        acc += d * d;
      }
    }
    // rare tail (S-1 > 256): correctness path, direct loads
    for (int k = tid + 256; k < S - 1; k += 256) {
      const int p0 = pos[k];
      const int p1 = pos[k + 1];
      const int cnt = p1 - p0 - 1;
      if (cnt > 0) {
        const int ta = p1 - 1;
        const float Pa = rowf[(swz(ta >> 2) << 2) | (ta & 3)] + cexc[ta >> 5];
        const float Pb = rowf[(swz(p0 >> 2) << 2) | (p0 & 3)] + cexc[p0 >> 5];
        const float mean = (Pa - Pb) / (float)cnt;
        const float d = wp[(size_t)(row0 + r) * W + (p0 >> 1)] - mean;
        acc += d * d;
      }
    }
    // protect buf[r&1] from iteration r+1's DMA overwrite of buf[(r+2)&1]
    BAR_LGKM();
  }

  // block reduction of acc -> one partial per block
  #pragma unroll
  for (int o = 32; o > 0; o >>= 1) acc += __shfl_down(acc, o);
  if (lane == 0) s_red[wid] = acc;
  __syncthreads();
  if (tid == 0) partials[blk] = s_red[0] + s_red[1] + s_red[2] + s_red[3];
}

// ---------------- kernel 3: deterministic final reduction ----------------
__global__ __launch_bounds__(256) void k_finalize(
    const float* __restrict__ partials, const int* __restrict__ validCount,
    float* __restrict__ out) {
  __shared__ float s_red[4];
  __shared__ int s_cnt[4];
  const int tid = threadIdx.x;
  const int lane = tid & 63;
  const int wid = tid >> 6;
  float s = 0.f;
  for (int i = tid; i < NPART; i += 256) s += partials[i];
  int cnt = 0;
  for (int i = tid; i < B; i += 256) cnt += validCount[i];
  for (int o = 32; o > 0; o >>= 1) {
    s += __shfl_down(s, o);
    cnt += __shfl_down(cnt, o);
  }
  if (lane == 0) { s_red[wid] = s; s_cnt[wid] = cnt; }
  __syncthreads();
  if (tid == 0) {
    const float total = s_red[0] + s_red[1] + s_red[2] + s_red[3];
    const int c = s_cnt[0] + s_cnt[1] + s_cnt[2] + s_cnt[3];
    out[0] = (c > 0) ? total / ((float)FDIM * (float)c) : 0.f;
  }
}

extern "C" void kernel_launch(void* const* d_in, const int* in_sizes, int n_in,
                              void* d_out, int out_size, void* d_ws, size_t ws_size,
                              hipStream_t stream) {
  const float* wp = (const float*)d_in[0];
  const float* cf = (const float*)d_in[1];
  const int* chars = (const int*)d_in[2];
  float* out = (float*)d_out;

  char* ws = (char*)d_ws;
  int* spacePos = (int*)ws;                            // B*T ints = 512 KB
  int* nspaces = (int*)(ws + (size_t)B * T * 4);       // B ints
  int* validCount = nspaces + B;                       // B ints
  float* partials = (float*)(validCount + B);          // NPART floats

  k_find_spaces<<<B, 1024, 0, stream>>>(chars, spacePos, nspaces, validCount);
  k_span_loss<<<NPART, 256, 0, stream>>>(wp, cf, spacePos, nspaces, partials);
  k_finalize<<<1, 256, 0, stream>>>(partials, validCount, out);
}

// Round 7
// 72.466 us; speedup vs baseline: 1.5009x; 1.0263x over previous
//
#include <hip/hip_runtime.h>

// WordSpanLoss: B=16, F=512, T=8192, W=4096, SPACE_TOKEN=63, STRIDE=2
// Fused: each block derives its batch's space positions itself (hidden under
// the row-0 cf DMA), then runs the prefix-sum span loss over 8 f-rows.

constexpr int SPACE_TOKEN = 63;
constexpr int B = 16;
constexpr int FDIM = 512;
constexpr int T = 8192;
constexpr int W = 4096;
constexpr int ROWS = 8;                   // f-rows per block
constexpr int NBLK = B * FDIM / ROWS;     // 1024 blocks
constexpr int SENT = T;                   // sentinel "position"

__device__ __forceinline__ int swz(int u) { return u ^ ((u >> 3) & 7); }

#define BAR_VM8() do { asm volatile("s_waitcnt vmcnt(8)" ::: "memory"); \
  __builtin_amdgcn_s_barrier(); asm volatile("" ::: "memory"); } while (0)
#define BAR_VM0() do { asm volatile("s_waitcnt vmcnt(0)" ::: "memory"); \
  __builtin_amdgcn_s_barrier(); asm volatile("" ::: "memory"); } while (0)
#define BAR_LGKM() do { asm volatile("s_waitcnt lgkmcnt(0)" ::: "memory"); \
  __builtin_amdgcn_s_barrier(); asm volatile("" ::: "memory"); } while (0)

__device__ __forceinline__ void stage_row(const float4* __restrict__ src,
                                          float* dst, int tid, int wid) {
  float4* d4 = (float4*)dst;
  #pragma unroll
  for (int i = 0; i < 8; ++i) {
    const int u = i * 256 + tid;                 // linear LDS slot
    const float4* gsrc = src + swz(u);           // per-lane swizzled source
    float4* ldst = d4 + (i * 256 + wid * 64);    // wave-uniform base
    __builtin_amdgcn_global_load_lds(
        (const __attribute__((address_space(1))) void*)(const void*)gsrc,
        (__attribute__((address_space(3))) void*)(void*)ldst, 16, 0, 0);
  }
}

__global__ __launch_bounds__(256) void k_fused(
    const float* __restrict__ wp, const float* __restrict__ cf,
    const int* __restrict__ chars, float* __restrict__ partials,
    int* __restrict__ batchValid) {
  const int blk = blockIdx.x;          // 0..NBLK-1
  const int row0 = blk * ROWS;         // first (b,f) row
  const int b = row0 >> 9;             // FDIM = 512
  __shared__ alignas(16) float buf[2][T];       // 64 KB
  __shared__ alignas(16) float csum[256];
  __shared__ alignas(16) float cexc[256];
  __shared__ int posL[260];                     // space positions 0..256
  __shared__ int s_wtot[4], s_wpair[4];
  __shared__ float s_red[4];
  const int tid = threadIdx.x;
  const int lane = tid & 63;
  const int wid = tid >> 6;
  const int* cb = chars + (size_t)b * T;

  // --- chars loads FIRST (oldest in vmcnt), coalesced int4 ---
  int4 creg[8];
  const int4* c4 = (const int4*)cb;
  #pragma unroll
  for (int i = 0; i < 8; ++i) creg[i] = c4[i * 256 + tid];

  // --- row-0 cf DMA (8 newest vmcnt entries per wave) ---
  stage_row((const float4*)(cf + (size_t)row0 * T), buf[0], tid, wid);

  // wait for chars only (all but the 8 newest = row-0 DMA still in flight)
  asm volatile("s_waitcnt vmcnt(8)" ::: "memory");

  // park chars in buf[1] (free until row-1 DMA), swizzled layout; init posL
  int4* b1 = (int4*)buf[1];
  #pragma unroll
  for (int i = 0; i < 8; ++i) b1[swz(i * 256 + tid)] = creg[i];
  posL[tid] = SENT;
  if (tid == 0) { posL[256] = SENT; posL[257] = SENT; }
  BAR_LGKM();

  // --- space scan: thread owns 32 contiguous chars ---
  int ch[32];
  #pragma unroll
  for (int i = 0; i < 8; ++i) {
    const int4 q = b1[swz(tid * 8 + i)];
    ch[i * 4 + 0] = q.x; ch[i * 4 + 1] = q.y;
    ch[i * 4 + 2] = q.z; ch[i * 4 + 3] = q.w;
  }
  int nxt = SPACE_TOKEN + 1;
  if (tid < 255) nxt = b1[swz((tid + 1) * 8)].x;   // first char of next thread

  int cnt = 0, pairs = 0;
  #pragma unroll
  for (int i = 0; i < 32; ++i) cnt += (ch[i] == SPACE_TOKEN);
  #pragma unroll
  for (int i = 0; i < 31; ++i)
    pairs += (ch[i] == SPACE_TOKEN) && (ch[i + 1] == SPACE_TOKEN);
  pairs += (ch[31] == SPACE_TOKEN) && (nxt == SPACE_TOKEN);

  int inc = cnt, pr = pairs;
  #pragma unroll
  for (int o = 1; o < 64; o <<= 1) {
    const int n = __shfl_up(inc, o);
    if (lane >= o) inc += n;
  }
  #pragma unroll
  for (int o = 32; o > 0; o >>= 1) pr += __shfl_down(pr, o);
  if (lane == 63) s_wtot[wid] = inc;
  if (lane == 0) s_wpair[wid] = pr;
  BAR_LGKM();

  int wexc = 0;
  for (int w = 0; w < wid; ++w) wexc += s_wtot[w];
  const int S = s_wtot[0] + s_wtot[1] + s_wtot[2] + s_wtot[3];
  const int P = s_wpair[0] + s_wpair[1] + s_wpair[2] + s_wpair[3];
  int rk = wexc + inc - cnt;            // exclusive rank of thread's 1st space
  #pragma unroll
  for (int i = 0; i < 32; ++i)
    if (ch[i] == SPACE_TOKEN) { if (rk < 257) posL[rk] = tid * 32 + i; ++rk; }
  BAR_LGKM();

  if ((blk & 63) == 0 && tid == 0)
    batchValid[b] = (S > 1 ? S - 1 : 0) - P;

  // --- per-thread span registers + wp prefetch (8 named scalars) ---
  const int p0r = posL[tid];
  const int p1r = posL[tid + 1];
  const int gidx = (p0r >> 1) & (W - 1);        // safe for sentinel
  const float* wpb = wp + (size_t)row0 * W + gidx;
  const float wv0 = wpb[0 * W];
  const float wv1 = wpb[1 * W];
  const float wv2 = wpb[2 * W];
  const float wv3 = wpb[3 * W];
  const float wv4 = wpb[4 * W];
  const float wv5 = wpb[5 * W];
  const float wv6 = wpb[6 * W];
  const float wv7 = wpb[7 * W];

  float acc = 0.f;
  #pragma unroll 1
  for (int r = 0; r < ROWS; ++r) {
    if (r + 1 < ROWS)
      stage_row((const float4*)(cf + (size_t)(row0 + r + 1) * T),
                buf[(r + 1) & 1], tid, wid);
    if (r + 1 < ROWS) { BAR_VM8(); } else { BAR_VM0(); }

    float* rowf = buf[r & 1];
    float4* r4 = (float4*)rowf;

    // phase b: per-thread 32-float in-register inclusive prefix
    float4 v[8];
    #pragma unroll
    for (int i = 0; i < 8; ++i) v[i] = r4[swz(tid * 8 + i)];
    float run = 0.f;
    #pragma unroll
    for (int i = 0; i < 8; ++i) {
      v[i].x = (run += v[i].x);
      v[i].y = (run += v[i].y);
      v[i].z = (run += v[i].z);
      v[i].w = (run += v[i].w);
    }
    #pragma unroll
    for (int i = 0; i < 8; ++i) r4[swz(tid * 8 + i)] = v[i];
    csum[tid] = run;
    BAR_LGKM();

    // phase c: wave 0 scans 256 chunk totals -> exclusive offsets
    if (tid < 64) {
      const float4 sv = ((const float4*)csum)[tid];
      const float l1 = sv.x + sv.y;
      const float l2 = l1 + sv.z;
      const float tot = l2 + sv.w;
      float pinc = tot;
      #pragma unroll
      for (int o = 1; o < 64; o <<= 1) {
        const float n = __shfl_up(pinc, o);
        if (tid >= o) pinc += n;
      }
      const float exc = pinc - tot;
      ((float4*)cexc)[tid] = make_float4(exc, exc + sv.x, exc + l1, exc + l2);
    }
    BAR_LGKM();

    // phase d: span evaluation from registers + LDS
    if (tid < S - 1) {
      const int scnt = p1r - p0r - 1;
      if (scnt > 0) {
        const int ta = p1r - 1;
        const float Pa = rowf[(swz(ta >> 2) << 2) | (ta & 3)] + cexc[ta >> 5];
        const float Pb = rowf[(swz(p0r >> 2) << 2) | (p0r & 3)] + cexc[p0r >> 5];
        const float mean = (Pa - Pb) / (float)scnt;
        const float wvr = (r == 0) ? wv0 : (r == 1) ? wv1 : (r == 2) ? wv2 :
                          (r == 3) ? wv3 : (r == 4) ? wv4 : (r == 5) ? wv5 :
                          (r == 6) ? wv6 : wv7;
        const float d = wvr - mean;
        acc += d * d;
      }
    }
    // correctness tail (S-1 > 256, never hit at bench stats): per-thread
    // sequential char walk evaluating spans k = 256+tid, 512+tid, ...
    if (S - 1 > 256) {
      int want = 256 + tid;
      if (want < S - 1) {
        int rank2 = 0;
        int p0 = -1;
        for (int t = 0; t < T; ++t) {
          if (cb[t] == SPACE_TOKEN) {
            if (rank2 == want) {
              p0 = t;
            } else if (rank2 == want + 1) {
              const int scnt = t - p0 - 1;
              if (scnt > 0) {
                const int ta = t - 1;
                const float Pa = rowf[(swz(ta >> 2) << 2) | (ta & 3)] + cexc[ta >> 5];
                const float Pb = rowf[(swz(p0 >> 2) << 2) | (p0 & 3)] + cexc[p0 >> 5];
                const float mean = (Pa - Pb) / (float)scnt;
                const float d = wp[(size_t)(row0 + r) * W + (p0 >> 1)] - mean;
                acc += d * d;
              }
              want += 256;
              if (want >= S - 1) break;
            }
            rank2++;
          }
        }
      }
    }
    BAR_LGKM();   // protect buf[r&1] before next iteration's DMA overwrite
  }

  // block reduction -> one partial per block
  #pragma unroll
  for (int o = 32; o > 0; o >>= 1) acc += __shfl_down(acc, o);
  if (lane == 0) s_red[wid] = acc;
  __syncthreads();
  if (tid == 0) partials[blk] = s_red[0] + s_red[1] + s_red[2] + s_red[3];
}

// ---------------- kernel 2: deterministic final reduction ----------------
__global__ __launch_bounds__(256) void k_finalize(
    const float* __restrict__ partials, const int* __restrict__ batchValid,
    float* __restrict__ out) {
  __shared__ float s_red[4];
  __shared__ int s_cnt[4];
  const int tid = threadIdx.x;
  const int lane = tid & 63;
  const int wid = tid >> 6;
  float s = 0.f;
  for (int i = tid; i < NBLK; i += 256) s += partials[i];
  int cnt = 0;
  for (int i = tid; i < B; i += 256) cnt += batchValid[i];
  for (int o = 32; o > 0; o >>= 1) {
    s += __shfl_down(s, o);
    cnt += __shfl_down(cnt, o);
  }
  if (lane == 0) { s_red[wid] = s; s_cnt[wid] = cnt; }
  __syncthreads();
  if (tid == 0) {
    const float total = s_red[0] + s_red[1] + s_red[2] + s_red[3];
    const int c = s_cnt[0] + s_cnt[1] + s_cnt[2] + s_cnt[3];
    out[0] = (c > 0) ? total / ((float)FDIM * (float)c) : 0.f;
  }
}

extern "C" void kernel_launch(void* const* d_in, const int* in_sizes, int n_in,
                              void* d_out, int out_size, void* d_ws, size_t ws_size,
                              hipStream_t stream) {
  const float* wp = (const float*)d_in[0];
  const float* cf = (const float*)d_in[1];
  const int* chars = (const int*)d_in[2];
  float* out = (float*)d_out;

  char* ws = (char*)d_ws;
  float* partials = (float*)ws;                 // NBLK floats
  int* batchValid = (int*)(ws + NBLK * 4);      // B ints

  k_fused<<<NBLK, 256, 0, stream>>>(wp, cf, chars, partials, batchValid);
  k_finalize<<<1, 256, 0, stream>>>(partials, batchValid, out);
}